// Round 4
// baseline (388.697 us; speedup 1.0000x reference)
//
#include <hip/hip_runtime.h>
#include <stdint.h>

#define NB 4
#define NH 8
#define SS 2048
#define EE 512
#define DD 64
#define MM (NB*SS)      // 8192
#define LDP 72          // padded LDS row (bf16 elems) for the GEMM kernel

typedef __attribute__((ext_vector_type(8))) __bf16 bf16x8;
typedef __attribute__((ext_vector_type(8))) unsigned short ushort8;
typedef __attribute__((ext_vector_type(4))) unsigned short ushort4v;
typedef __attribute__((ext_vector_type(4))) float f32x4;

__device__ __forceinline__ uint16_t f2bf(float f) {
    union { float f; uint32_t u; } v; v.f = f;
    return (uint16_t)((v.u + 0x7fffu + ((v.u >> 16) & 1u)) >> 16);   // RNE
}
__device__ __forceinline__ float bf2f(uint16_t h) {
    union { uint32_t u; float f; } v; v.u = ((uint32_t)h) << 16;
    return v.f;
}

// global -> LDS direct copy, 16B per lane (addrspace cast via uintptr_t)
__device__ __forceinline__ void gl16(const uint16_t* g, uint16_t* l) {
    __builtin_amdgcn_global_load_lds(
        reinterpret_cast<const __attribute__((address_space(1))) uint32_t*>(
            reinterpret_cast<uintptr_t>(g)),
        reinterpret_cast<__attribute__((address_space(3))) uint32_t*>(
            reinterpret_cast<uintptr_t>(l)),
        16, 0, 0);
}

// ---------------- split fp32 -> bf16 hi + bf16 lo ----------------
__global__ __launch_bounds__(256) void split_k(const float* __restrict__ in,
        uint16_t* __restrict__ hi, uint16_t* __restrict__ lo, int n4) {
    int i = blockIdx.x * 256 + threadIdx.x;
    if (i >= n4) return;
    f32x4 x = reinterpret_cast<const f32x4*>(in)[i];
    ushort4v h, l;
#pragma unroll
    for (int j = 0; j < 4; j++) {
        uint16_t hh = f2bf(x[j]);
        h[j] = hh;
        l[j] = f2bf(x[j] - bf2f(hh));
    }
    reinterpret_cast<ushort4v*>(hi)[i] = h;
    reinterpret_cast<ushort4v*>(lo)[i] = l;
}

// ---------------- split-bf16 3-pass NT GEMM: C = alpha*(A@B^T + bias) ----------------
__global__ __launch_bounds__(256, 2)
void gemm_nt(const uint16_t* __restrict__ Ah, const uint16_t* __restrict__ Al,
             const uint16_t* __restrict__ Bh, const uint16_t* __restrict__ Bl,
             const float* __restrict__ bias, float alpha, int K, int N, int mode,
             uint16_t* __restrict__ Oh, uint16_t* __restrict__ Ol, float* __restrict__ Of)
{
    __shared__ uint16_t sAh[128*LDP], sAl[128*LDP], sBh[128*LDP], sBl[128*LDP];
    const int t = threadIdx.x;
    const int lane = t & 63;
    const int wave = t >> 6;
    const int m0 = blockIdx.x * 128;
    const int n0 = blockIdx.y * 128;

    f32x4 zero = {0.f, 0.f, 0.f, 0.f};
    f32x4 acc[4][4];
#pragma unroll
    for (int i = 0; i < 4; i++)
#pragma unroll
        for (int j = 0; j < 4; j++) acc[i][j] = zero;

    const int sr = t >> 3;        // 0..31
    const int sc = (t & 7) * 8;   // 0..56

    for (int k0 = 0; k0 < K; k0 += 64) {
#pragma unroll
        for (int p = 0; p < 4; p++) {
            const int row = sr + 32 * p;
            const size_t ga = (size_t)(m0 + row) * K + k0 + sc;
            const size_t gb = (size_t)(n0 + row) * K + k0 + sc;
            *reinterpret_cast<ushort8*>(&sAh[row*LDP + sc]) = *reinterpret_cast<const ushort8*>(&Ah[ga]);
            *reinterpret_cast<ushort8*>(&sAl[row*LDP + sc]) = *reinterpret_cast<const ushort8*>(&Al[ga]);
            *reinterpret_cast<ushort8*>(&sBh[row*LDP + sc]) = *reinterpret_cast<const ushort8*>(&Bh[gb]);
            *reinterpret_cast<ushort8*>(&sBl[row*LDP + sc]) = *reinterpret_cast<const ushort8*>(&Bl[gb]);
        }
        __syncthreads();
        const int mw = (wave >> 1) * 64;
        const int nw = (wave & 1) * 64;
#pragma unroll
        for (int ks = 0; ks < 2; ks++) {
            const int kk = ks*32 + (lane >> 4) * 8;
            bf16x8 fah[4], fal[4], fbh[4], fbl[4];
#pragma unroll
            for (int i = 0; i < 4; i++) {
                const int ra = (mw + 16*i + (lane & 15)) * LDP + kk;
                fah[i] = *reinterpret_cast<const bf16x8*>(&sAh[ra]);
                fal[i] = *reinterpret_cast<const bf16x8*>(&sAl[ra]);
                const int rb = (nw + 16*i + (lane & 15)) * LDP + kk;
                fbh[i] = *reinterpret_cast<const bf16x8*>(&sBh[rb]);
                fbl[i] = *reinterpret_cast<const bf16x8*>(&sBl[rb]);
            }
#pragma unroll
            for (int i = 0; i < 4; i++)
#pragma unroll
                for (int j = 0; j < 4; j++) {
                    acc[i][j] = __builtin_amdgcn_mfma_f32_16x16x32_bf16(fah[i], fbh[j], acc[i][j], 0, 0, 0);
                    acc[i][j] = __builtin_amdgcn_mfma_f32_16x16x32_bf16(fah[i], fbl[j], acc[i][j], 0, 0, 0);
                    acc[i][j] = __builtin_amdgcn_mfma_f32_16x16x32_bf16(fal[i], fbh[j], acc[i][j], 0, 0, 0);
                }
        }
        __syncthreads();
    }

    const int mw = (wave >> 1) * 64;
    const int nw = (wave & 1) * 64;
#pragma unroll
    for (int j = 0; j < 4; j++) {
        const int col = n0 + nw + 16*j + (lane & 15);
        const float bv = bias ? bias[col] : 0.f;
#pragma unroll
        for (int i = 0; i < 4; i++) {
            const int rowb = m0 + mw + 16*i + ((lane >> 4) << 2);
#pragma unroll
            for (int r4 = 0; r4 < 4; r4++) {
                const int m = rowb + r4;
                const float val = (acc[i][j][r4] + bv) * alpha;
                if (mode == 2) {
                    Of[(size_t)m * N + col] = val;
                } else {
                    const int bb = m >> 11, s = m & (SS-1), h = col >> 6, d = col & 63;
                    const size_t idx = (((size_t)(bb*NH + h)) * SS + s) * DD + d;
                    const uint16_t hh = f2bf(val);
                    Oh[idx] = hh;
                    if (mode == 0) Ol[idx] = f2bf(val - bf2f(hh));
                }
            }
        }
    }
}

// ---------------- fused flash attention with recompute ----------------
// LDS: bufA = K tile (hi 16KB + lo 16KB, XOR-swizzled, linear rows for gload_lds)
//      bufB = phase-1 K double-buffer partner / phase-2 W bf16 tile (swizzled)
//      vbuf = V^T tile [64][128] bf16 (swizzled)
// Q pre-scaled by 0.125*log2(e): softmax uses exp2 directly.
__global__ __launch_bounds__(256, 2)
void attn_fused(const uint16_t* __restrict__ Qh, const uint16_t* __restrict__ Ql,
                const uint16_t* __restrict__ Kh, const uint16_t* __restrict__ Kl,
                const uint16_t* __restrict__ Vh,
                float* __restrict__ attn,
                uint16_t* __restrict__ Oh, uint16_t* __restrict__ Ol)
{
    __shared__ __align__(16) uint16_t smem[40960];   // 80 KB -> 2 blocks/CU
    uint16_t* bufA = smem;
    uint16_t* bufB = smem + 16384;
    uint16_t* vbuf = smem + 32768;

    const int t = threadIdx.x, lane = t & 63, wave = t >> 6;
    // XCD-aware bijective remap: all 16 qt-blocks of a head land on one XCD
    const int f = blockIdx.x + (int)gridDim.x * blockIdx.y;   // 0..511
    const int bh = (f & 7) + 8 * ((f >> 3) & 3);
    const int qt = f >> 5;

    const size_t hb = (size_t)bh * SS * DD;
    const uint16_t* kbh = Kh + hb;
    const uint16_t* kbl = Kl + hb;
    const uint16_t* vbs = Vh + hb;

    const int l15 = lane & 15;
    const int l16 = lane >> 4;

    // staging geometry: 8 rounds x 256 lanes x 16B = 32KB (hi rounds 0-3, lo 4-7)
    const int r8 = t >> 3;                 // 0..31 (row within 32-row group)
    const int c8 = t & 7;                  // dest chunk
    const int csrc = (c8 ^ (r8 & 7)) * 8;  // pre-swizzled source column (inverse XOR)
    auto stage_k = [&](uint16_t* buf, int ktile) {
#pragma unroll
        for (int p = 0; p < 8; p++) {
            const int row = (p & 3) * 32 + r8;
            const uint16_t* g = ((p >> 2) ? kbl : kbh) + (size_t)(ktile * 128 + row) * DD + csrc;
            gl16(g, buf + p * 2048 + wave * 512);
        }
    };

    // ---- Q fragments in registers (persistent) ----
    bf16x8 qfh[2][2], qfl[2][2];
#pragma unroll
    for (int i = 0; i < 2; i++)
#pragma unroll
        for (int ks = 0; ks < 2; ks++) {
            const size_t qa = hb + (size_t)(qt*128 + wave*32 + 16*i + l15) * DD + ks*32 + l16*8;
            qfh[i][ks] = *reinterpret_cast<const bf16x8*>(&Qh[qa]);
            qfl[i][ks] = *reinterpret_cast<const bf16x8*>(&Ql[qa]);
        }

    float m_run[2][4], l_run[2][4];
#pragma unroll
    for (int i = 0; i < 2; i++)
#pragma unroll
        for (int r = 0; r < 4; r++) { m_run[i][r] = -3.0e38f; l_run[i][r] = 0.f; }

    f32x4 zero = {0.f, 0.f, 0.f, 0.f};

    // ================= phase 1: online max & sum (K double-buffered) =================
    stage_k(bufA, 0);
    __syncthreads();
#pragma unroll 1
    for (int kt = 0; kt < 16; kt++) {
        uint16_t* cur = (kt & 1) ? bufB : bufA;
        if (kt < 15) stage_k((kt & 1) ? bufA : bufB, kt + 1);

        f32x4 accs[2][8];
#pragma unroll
        for (int i = 0; i < 2; i++)
#pragma unroll
            for (int j = 0; j < 8; j++) accs[i][j] = zero;

#pragma unroll
        for (int ks = 0; ks < 2; ks++) {
#pragma unroll
            for (int j = 0; j < 8; j++) {
                const int off = (16*j + l15)*64 + (((ks*4 + l16) ^ (l15 & 7)) * 8);
                bf16x8 fbh = *reinterpret_cast<const bf16x8*>(cur + off);
                bf16x8 fbl = *reinterpret_cast<const bf16x8*>(cur + 8192 + off);
#pragma unroll
                for (int i = 0; i < 2; i++) {
                    accs[i][j] = __builtin_amdgcn_mfma_f32_16x16x32_bf16(qfh[i][ks], fbh, accs[i][j], 0, 0, 0);
                    accs[i][j] = __builtin_amdgcn_mfma_f32_16x16x32_bf16(qfh[i][ks], fbl, accs[i][j], 0, 0, 0);
                    accs[i][j] = __builtin_amdgcn_mfma_f32_16x16x32_bf16(qfl[i][ks], fbh, accs[i][j], 0, 0, 0);
                }
            }
        }

#pragma unroll
        for (int i = 0; i < 2; i++)
#pragma unroll
            for (int r = 0; r < 4; r++) {
                float tm = accs[i][0][r];
#pragma unroll
                for (int j = 1; j < 8; j++) tm = fmaxf(tm, accs[i][j][r]);
#pragma unroll
                for (int o = 1; o < 16; o <<= 1) tm = fmaxf(tm, __shfl_xor(tm, o));
                const float mn = fmaxf(m_run[i][r], tm);
                const float c = __builtin_amdgcn_exp2f(m_run[i][r] - mn);
                float ps = 0.f;
#pragma unroll
                for (int j = 0; j < 8; j++) ps += __builtin_amdgcn_exp2f(accs[i][j][r] - mn);
                l_run[i][r] = l_run[i][r] * c + ps;
                m_run[i][r] = mn;
            }
        __syncthreads();
    }

    // finalize: full-row inverse sums
#pragma unroll
    for (int i = 0; i < 2; i++)
#pragma unroll
        for (int r = 0; r < 4; r++) {
            float s = l_run[i][r];
#pragma unroll
            for (int o = 1; o < 16; o <<= 1) s += __shfl_xor(s, o);
            l_run[i][r] = 1.0f / s;
        }

    f32x4 acco[2][4];
#pragma unroll
    for (int i = 0; i < 2; i++)
#pragma unroll
        for (int j = 0; j < 4; j++) acco[i][j] = zero;

    float* wbase = attn + ((size_t)bh * SS + qt*128) * SS;
    const int k0  = (t & 63) * 2;   // V k-pair
    const int dc0 = t >> 6;         // V d-chunk base

    // ================= phase 2: recompute, write weights, PV =================
    stage_k(bufA, 0);
    __syncthreads();
#pragma unroll 1
    for (int kt = 0; kt < 16; kt++) {
        // 1. issue V[kt] global loads early (consumed after bar1)
        ushort8 vr[2][2];
#pragma unroll
        for (int u = 0; u < 2; u++) {
            const uint16_t* vg = vbs + (size_t)(kt*128 + k0) * DD + (dc0 + 4*u)*8;
            vr[u][0] = *reinterpret_cast<const ushort8*>(vg);
            vr[u][1] = *reinterpret_cast<const ushort8*>(vg + DD);
        }

        // 2. QK^T from bufA (bit-identical to phase 1)
        f32x4 accs[2][8];
#pragma unroll
        for (int i = 0; i < 2; i++)
#pragma unroll
            for (int j = 0; j < 8; j++) accs[i][j] = zero;
#pragma unroll
        for (int ks = 0; ks < 2; ks++) {
#pragma unroll
            for (int j = 0; j < 8; j++) {
                const int off = (16*j + l15)*64 + (((ks*4 + l16) ^ (l15 & 7)) * 8);
                bf16x8 fbh = *reinterpret_cast<const bf16x8*>(bufA + off);
                bf16x8 fbl = *reinterpret_cast<const bf16x8*>(bufA + 8192 + off);
#pragma unroll
                for (int i = 0; i < 2; i++) {
                    accs[i][j] = __builtin_amdgcn_mfma_f32_16x16x32_bf16(qfh[i][ks], fbh, accs[i][j], 0, 0, 0);
                    accs[i][j] = __builtin_amdgcn_mfma_f32_16x16x32_bf16(qfh[i][ks], fbl, accs[i][j], 0, 0, 0);
                    accs[i][j] = __builtin_amdgcn_mfma_f32_16x16x32_bf16(qfl[i][ks], fbh, accs[i][j], 0, 0, 0);
                }
            }
        }

        // 3. normalize in place
#pragma unroll
        for (int i = 0; i < 2; i++)
#pragma unroll
            for (int r = 0; r < 4; r++) {
                const float mf = m_run[i][r], iv = l_run[i][r];
#pragma unroll
                for (int j = 0; j < 8; j++)
                    accs[i][j][r] = __builtin_amdgcn_exp2f(accs[i][j][r] - mf) * iv;
            }

        __syncthreads();                       // bar1: all waves done reading K in bufA
        if (kt < 15) stage_k(bufA, kt + 1);    // prefetch next K (hidden until bar2)

        // 6. weight stores (final output 1, fp32)
#pragma unroll
        for (int i = 0; i < 2; i++)
#pragma unroll
            for (int r = 0; r < 4; r++) {
                const int row = wave*32 + 16*i + l16*4 + r;
                float* wout = wbase + (size_t)row * SS + kt*128 + l15;
#pragma unroll
                for (int j = 0; j < 8; j++) wout[16*j] = accs[i][j][r];
            }

        // 7. W bf16 -> bufB (swizzled), V^T -> vbuf (swizzled, packed pairs)
#pragma unroll
        for (int i = 0; i < 2; i++)
#pragma unroll
            for (int r = 0; r < 4; r++) {
                const int row = wave*32 + 16*i + l16*4 + r;
                const int rx = row & 7;
#pragma unroll
                for (int j = 0; j < 8; j++) {
                    const int off = row*128 + (((2*j + (l15 >> 3)) ^ rx) * 8) + (l15 & 7);
                    bufB[off] = f2bf(accs[i][j][r]);
                }
            }
#pragma unroll
        for (int u = 0; u < 2; u++) {
            const int dc = dc0 + 4*u;
#pragma unroll
            for (int e = 0; e < 8; e++) {
                const int d = dc*8 + e;
                const int off = d*128 + ((((k0 >> 3) ^ (d & 7))) * 8) + (k0 & 7);
                const uint32_t pack = (uint32_t)(unsigned short)vr[u][0][e]
                                    | ((uint32_t)(unsigned short)vr[u][1][e] << 16);
                *reinterpret_cast<uint32_t*>(vbuf + off) = pack;
            }
        }
        __syncthreads();                       // bar2: W/V^T visible, K prefetch drained

        // 9. PV: O += W @ V
#pragma unroll
        for (int ks = 0; ks < 4; ks++) {
            bf16x8 wa[2], vb[4];
#pragma unroll
            for (int i = 0; i < 2; i++) {
                const int row = wave*32 + 16*i + l15;
                wa[i] = *reinterpret_cast<const bf16x8*>(bufB + row*128 + (((ks*4 + l16) ^ (row & 7)) * 8));
            }
#pragma unroll
            for (int j = 0; j < 4; j++) {
                const int d = 16*j + l15;
                vb[j] = *reinterpret_cast<const bf16x8*>(vbuf + d*128 + (((ks*4 + l16) ^ (d & 7)) * 8));
            }
#pragma unroll
            for (int i = 0; i < 2; i++)
#pragma unroll
                for (int j = 0; j < 4; j++)
                    acco[i][j] = __builtin_amdgcn_mfma_f32_16x16x32_bf16(wa[i], vb[j], acco[i][j], 0, 0, 0);
        }
    }

    // epilogue: attn_output split-bf16 into [b, s, h*64+d]
    const int b = bh >> 3, h = bh & 7;
#pragma unroll
    for (int i = 0; i < 2; i++)
#pragma unroll
        for (int j = 0; j < 4; j++)
#pragma unroll
            for (int r4 = 0; r4 < 4; r4++) {
                const int srow = qt*128 + wave*32 + 16*i + (l16 << 2) + r4;
                const int col = h*64 + 16*j + l15;
                const size_t idx = ((size_t)b * SS + srow) * (size_t)EE + col;
                const float val = acco[i][j][r4];
                const uint16_t hh = f2bf(val);
                Oh[idx] = hh;
                Ol[idx] = f2bf(val - bf2f(hh));
            }
}

extern "C" void kernel_launch(void* const* d_in, const int* in_sizes, int n_in,
                              void* d_out, int out_size, void* d_ws, size_t ws_size,
                              hipStream_t stream)
{
    const float* x  = (const float*)d_in[0];
    const float* Wq = (const float*)d_in[1];
    const float* bq = (const float*)d_in[2];
    const float* Wk = (const float*)d_in[3];
    const float* bk = (const float*)d_in[4];
    const float* Wv = (const float*)d_in[5];
    const float* bv = (const float*)d_in[6];
    const float* Wo = (const float*)d_in[7];
    const float* bo = (const float*)d_in[8];

    float* outF = (float*)d_out;
    float* attn = outF + (size_t)MM * EE;   // output 1 region (normalized weights)

    const size_t NXE = (size_t)MM * EE;     // 4,194,304
    const size_t NW  = (size_t)EE * EE;     // 262,144
    uint16_t* p = (uint16_t*)d_ws;
    uint16_t* xh  = p;            p += NXE;
    uint16_t* xl  = p;            p += NXE;
    uint16_t* wqh = p;            p += NW;
    uint16_t* wql = p;            p += NW;
    uint16_t* wkh = p;            p += NW;
    uint16_t* wkl = p;            p += NW;
    uint16_t* wvh = p;            p += NW;
    uint16_t* wvl = p;            p += NW;
    uint16_t* woh = p;            p += NW;
    uint16_t* wol = p;            p += NW;
    uint16_t* qh  = p;            p += NXE;
    uint16_t* ql  = p;            p += NXE;
    uint16_t* kh  = p;            p += NXE;
    uint16_t* kl  = p;            p += NXE;
    uint16_t* vh  = p;            p += NXE;
    uint16_t* ah  = p;            p += NXE;
    uint16_t* al  = p;            p += NXE;

    split_k<<<(int)((NXE/4 + 255)/256), 256, 0, stream>>>(x,  xh,  xl,  (int)(NXE/4));
    split_k<<<(int)((NW /4 + 255)/256), 256, 0, stream>>>(Wq, wqh, wql, (int)(NW/4));
    split_k<<<(int)((NW /4 + 255)/256), 256, 0, stream>>>(Wk, wkh, wkl, (int)(NW/4));
    split_k<<<(int)((NW /4 + 255)/256), 256, 0, stream>>>(Wv, wvh, wvl, (int)(NW/4));
    split_k<<<(int)((NW /4 + 255)/256), 256, 0, stream>>>(Wo, woh, wol, (int)(NW/4));

    dim3 g(MM/128, EE/128);
    // Q scaled by 0.125*log2(e): scores land in log2 units -> softmax uses exp2 directly
    const float qscale = 0.125f * 1.44269504088896340736f;
    gemm_nt<<<g, 256, 0, stream>>>(xh, xl, wqh, wql, bq, qscale, EE, EE, 0, qh, ql, nullptr);
    gemm_nt<<<g, 256, 0, stream>>>(xh, xl, wkh, wkl, bk, 1.0f,   EE, EE, 0, kh, kl, nullptr);
    gemm_nt<<<g, 256, 0, stream>>>(xh, xl, wvh, wvl, bv, 1.0f,   EE, EE, 1, vh, nullptr, nullptr);

    attn_fused<<<dim3(SS/128, NB*NH), 256, 0, stream>>>(qh, ql, kh, kl, vh, attn, ah, al);

    gemm_nt<<<g, 256, 0, stream>>>(ah, al, woh, wol, bo, 1.0f, EE, EE, 2, nullptr, nullptr, outF);
}

// Round 5
// 334.540 us; speedup vs baseline: 1.1619x; 1.1619x over previous
//
#include <hip/hip_runtime.h>
#include <stdint.h>

#define NB 4
#define NH 8
#define SS 2048
#define EE 512
#define DD 64
#define MM (NB*SS)      // 8192
#define LDP 72          // padded LDS row (bf16 elems) for K-dim-64 tiles
#define LDW 136         // padded LDS row for 128-wide W / V^T tiles

typedef __attribute__((ext_vector_type(8))) __bf16 bf16x8;
typedef __attribute__((ext_vector_type(8))) unsigned short ushort8;
typedef __attribute__((ext_vector_type(4))) unsigned short ushort4v;
typedef __attribute__((ext_vector_type(4))) float f32x4;

__device__ __forceinline__ uint16_t f2bf(float f) {
    union { float f; uint32_t u; } v; v.f = f;
    return (uint16_t)((v.u + 0x7fffu + ((v.u >> 16) & 1u)) >> 16);   // RNE
}
__device__ __forceinline__ float bf2f(uint16_t h) {
    union { uint32_t u; float f; } v; v.u = ((uint32_t)h) << 16;
    return v.f;
}

// ---------------- split fp32 -> bf16 hi + bf16 lo ----------------
__global__ __launch_bounds__(256) void split_k(const float* __restrict__ in,
        uint16_t* __restrict__ hi, uint16_t* __restrict__ lo, int n4) {
    int i = blockIdx.x * 256 + threadIdx.x;
    if (i >= n4) return;
    f32x4 x = reinterpret_cast<const f32x4*>(in)[i];
    ushort4v h, l;
#pragma unroll
    for (int j = 0; j < 4; j++) {
        uint16_t hh = f2bf(x[j]);
        h[j] = hh;
        l[j] = f2bf(x[j] - bf2f(hh));
    }
    reinterpret_cast<ushort4v*>(hi)[i] = h;
    reinterpret_cast<ushort4v*>(lo)[i] = l;
}

// ---------------- merged QKV projection: [8192x512] @ [1536x512]^T, split-bf16 3-pass ----------------
// B rows 0..511 = Wq, 512..1023 = Wk, 1024..1535 = Wv.
// Epilogue routes by segment: Q -> (qh,ql) scaled by qscale; K -> (kh,kl); V -> vh.
__global__ __launch_bounds__(256, 2)
void gemm_qkv(const uint16_t* __restrict__ Ah, const uint16_t* __restrict__ Al,
              const uint16_t* __restrict__ Bh, const uint16_t* __restrict__ Bl,
              const float* __restrict__ bq, const float* __restrict__ bk,
              const float* __restrict__ bv, float qscale,
              uint16_t* __restrict__ qh, uint16_t* __restrict__ ql,
              uint16_t* __restrict__ kh, uint16_t* __restrict__ kl,
              uint16_t* __restrict__ vh)
{
    __shared__ uint16_t sAh[128*LDP], sAl[128*LDP], sBh[128*LDP], sBl[128*LDP];
    const int t = threadIdx.x;
    const int lane = t & 63;
    const int wave = t >> 6;
    const int m0 = blockIdx.x * 128;
    const int n0 = blockIdx.y * 128;

    f32x4 zero = {0.f, 0.f, 0.f, 0.f};
    f32x4 acc[4][4];
#pragma unroll
    for (int i = 0; i < 4; i++)
#pragma unroll
        for (int j = 0; j < 4; j++) acc[i][j] = zero;

    const int sr = t >> 3;        // 0..31
    const int sc = (t & 7) * 8;   // 0..56

    for (int k0 = 0; k0 < EE; k0 += 64) {
#pragma unroll
        for (int p = 0; p < 4; p++) {
            const int row = sr + 32 * p;
            const size_t ga = (size_t)(m0 + row) * EE + k0 + sc;
            const size_t gb = (size_t)(n0 + row) * EE + k0 + sc;
            *reinterpret_cast<ushort8*>(&sAh[row*LDP + sc]) = *reinterpret_cast<const ushort8*>(&Ah[ga]);
            *reinterpret_cast<ushort8*>(&sAl[row*LDP + sc]) = *reinterpret_cast<const ushort8*>(&Al[ga]);
            *reinterpret_cast<ushort8*>(&sBh[row*LDP + sc]) = *reinterpret_cast<const ushort8*>(&Bh[gb]);
            *reinterpret_cast<ushort8*>(&sBl[row*LDP + sc]) = *reinterpret_cast<const ushort8*>(&Bl[gb]);
        }
        __syncthreads();
        const int mw = (wave >> 1) * 64;
        const int nw = (wave & 1) * 64;
#pragma unroll
        for (int ks = 0; ks < 2; ks++) {
            const int kk = ks*32 + (lane >> 4) * 8;
            bf16x8 fah[4], fal[4], fbh[4], fbl[4];
#pragma unroll
            for (int i = 0; i < 4; i++) {
                const int ra = (mw + 16*i + (lane & 15)) * LDP + kk;
                fah[i] = *reinterpret_cast<const bf16x8*>(&sAh[ra]);
                fal[i] = *reinterpret_cast<const bf16x8*>(&sAl[ra]);
                const int rb = (nw + 16*i + (lane & 15)) * LDP + kk;
                fbh[i] = *reinterpret_cast<const bf16x8*>(&sBh[rb]);
                fbl[i] = *reinterpret_cast<const bf16x8*>(&sBl[rb]);
            }
#pragma unroll
            for (int i = 0; i < 4; i++)
#pragma unroll
                for (int j = 0; j < 4; j++) {
                    acc[i][j] = __builtin_amdgcn_mfma_f32_16x16x32_bf16(fah[i], fbh[j], acc[i][j], 0, 0, 0);
                    acc[i][j] = __builtin_amdgcn_mfma_f32_16x16x32_bf16(fah[i], fbl[j], acc[i][j], 0, 0, 0);
                    acc[i][j] = __builtin_amdgcn_mfma_f32_16x16x32_bf16(fal[i], fbh[j], acc[i][j], 0, 0, 0);
                }
        }
        __syncthreads();
    }

    const int mw = (wave >> 1) * 64;
    const int nw = (wave & 1) * 64;
#pragma unroll
    for (int j = 0; j < 4; j++) {
        const int col = n0 + nw + 16*j + (lane & 15);   // 0..1535
        const int seg = col >> 9;                        // 0=Q 1=K 2=V
        const int c   = col & 511;
        const float bias = (seg == 0 ? bq : (seg == 1 ? bk : bv))[c];
        const float scale = (seg == 0) ? qscale : 1.0f;
        const int h = c >> 6, d = c & 63;
#pragma unroll
        for (int i = 0; i < 4; i++) {
            const int rowb = m0 + mw + 16*i + ((lane >> 4) << 2);
#pragma unroll
            for (int r4 = 0; r4 < 4; r4++) {
                const int m = rowb + r4;
                const float val = (acc[i][j][r4] + bias) * scale;
                const int bb = m >> 11, s = m & (SS-1);
                const size_t idx = (((size_t)(bb*NH + h)) * SS + s) * DD + d;
                const uint16_t hi = f2bf(val);
                if (seg == 0)      { qh[idx] = hi; ql[idx] = f2bf(val - bf2f(hi)); }
                else if (seg == 1) { kh[idx] = hi; kl[idx] = f2bf(val - bf2f(hi)); }
                else               { vh[idx] = hi; }
            }
        }
    }
}

// ---------------- out-projection: [8192x512] @ [512x512]^T + bo, fp32 out, BM=64 ----------------
__global__ __launch_bounds__(256, 2)
void gemm_out(const uint16_t* __restrict__ Ah, const uint16_t* __restrict__ Al,
              const uint16_t* __restrict__ Bh, const uint16_t* __restrict__ Bl,
              const float* __restrict__ bo, float* __restrict__ Of)
{
    __shared__ uint16_t sAh[64*LDP], sAl[64*LDP], sBh[128*LDP], sBl[128*LDP];
    const int t = threadIdx.x;
    const int lane = t & 63;
    const int wave = t >> 6;
    const int m0 = blockIdx.x * 64;
    const int n0 = blockIdx.y * 128;

    f32x4 zero = {0.f, 0.f, 0.f, 0.f};
    f32x4 acc[2][4];
#pragma unroll
    for (int i = 0; i < 2; i++)
#pragma unroll
        for (int j = 0; j < 4; j++) acc[i][j] = zero;

    const int sr = t >> 3;        // 0..31
    const int sc = (t & 7) * 8;   // 0..56

    for (int k0 = 0; k0 < EE; k0 += 64) {
#pragma unroll
        for (int p = 0; p < 2; p++) {
            const int row = sr + 32 * p;
            const size_t ga = (size_t)(m0 + row) * EE + k0 + sc;
            *reinterpret_cast<ushort8*>(&sAh[row*LDP + sc]) = *reinterpret_cast<const ushort8*>(&Ah[ga]);
            *reinterpret_cast<ushort8*>(&sAl[row*LDP + sc]) = *reinterpret_cast<const ushort8*>(&Al[ga]);
        }
#pragma unroll
        for (int p = 0; p < 4; p++) {
            const int row = sr + 32 * p;
            const size_t gb = (size_t)(n0 + row) * EE + k0 + sc;
            *reinterpret_cast<ushort8*>(&sBh[row*LDP + sc]) = *reinterpret_cast<const ushort8*>(&Bh[gb]);
            *reinterpret_cast<ushort8*>(&sBl[row*LDP + sc]) = *reinterpret_cast<const ushort8*>(&Bl[gb]);
        }
        __syncthreads();
        const int mw = (wave >> 1) * 32;
        const int nw = (wave & 1) * 64;
#pragma unroll
        for (int ks = 0; ks < 2; ks++) {
            const int kk = ks*32 + (lane >> 4) * 8;
            bf16x8 fah[2], fal[2], fbh[4], fbl[4];
#pragma unroll
            for (int i = 0; i < 2; i++) {
                const int ra = (mw + 16*i + (lane & 15)) * LDP + kk;
                fah[i] = *reinterpret_cast<const bf16x8*>(&sAh[ra]);
                fal[i] = *reinterpret_cast<const bf16x8*>(&sAl[ra]);
            }
#pragma unroll
            for (int j = 0; j < 4; j++) {
                const int rb = (nw + 16*j + (lane & 15)) * LDP + kk;
                fbh[j] = *reinterpret_cast<const bf16x8*>(&sBh[rb]);
                fbl[j] = *reinterpret_cast<const bf16x8*>(&sBl[rb]);
            }
#pragma unroll
            for (int i = 0; i < 2; i++)
#pragma unroll
                for (int j = 0; j < 4; j++) {
                    acc[i][j] = __builtin_amdgcn_mfma_f32_16x16x32_bf16(fah[i], fbh[j], acc[i][j], 0, 0, 0);
                    acc[i][j] = __builtin_amdgcn_mfma_f32_16x16x32_bf16(fah[i], fbl[j], acc[i][j], 0, 0, 0);
                    acc[i][j] = __builtin_amdgcn_mfma_f32_16x16x32_bf16(fal[i], fbh[j], acc[i][j], 0, 0, 0);
                }
        }
        __syncthreads();
    }

    const int mw = (wave >> 1) * 32;
    const int nw = (wave & 1) * 64;
#pragma unroll
    for (int j = 0; j < 4; j++) {
        const int col = n0 + nw + 16*j + (lane & 15);
        const float bv = bo[col];
#pragma unroll
        for (int i = 0; i < 2; i++) {
            const int rowb = m0 + mw + 16*i + ((lane >> 4) << 2);
#pragma unroll
            for (int r4 = 0; r4 < 4; r4++)
                Of[(size_t)(rowb + r4) * EE + col] = acc[i][j][r4] + bv;
        }
    }
}

// ---------------- fused flash attention (round-2 known-good version) ----------------
// Q pre-scaled by 0.125*log2(e), so scores are in log2 units: softmax via exp2.
__global__ __launch_bounds__(256, 2)
void attn_fused(const uint16_t* __restrict__ Qh, const uint16_t* __restrict__ Ql,
                const uint16_t* __restrict__ Kh, const uint16_t* __restrict__ Kl,
                const uint16_t* __restrict__ Vh,
                float* __restrict__ attn,
                uint16_t* __restrict__ Oh, uint16_t* __restrict__ Ol)
{
    __shared__ uint16_t smem[128*LDP*2 + 64*LDW];
    uint16_t* skh  = smem;                 // K hi tile [128][LDP]
    uint16_t* skl  = smem + 128*LDP;       // K lo tile [128][LDP]
    uint16_t* wlds = smem;                 // overlay: W bf16 tile [128][LDW]
    uint16_t* svt  = smem + 128*LDP*2;     // V^T tile [64][LDW]

    const int t = threadIdx.x, lane = t & 63, wave = t >> 6;
    const int qt = blockIdx.x, bh = blockIdx.y;
    const size_t hb = (size_t)bh * SS * DD;
    const uint16_t* kbh = Kh + hb;
    const uint16_t* kbl = Kl + hb;
    const uint16_t* vbs = Vh + hb;

    const int l15 = lane & 15;
    const int l16 = lane >> 4;
    const int sr = t >> 3;        // 0..31
    const int sc = (t & 7) * 8;   // 0..56

    // ---- Q fragments in registers (persistent) ----
    bf16x8 qfh[2][2], qfl[2][2];
#pragma unroll
    for (int i = 0; i < 2; i++)
#pragma unroll
        for (int ks = 0; ks < 2; ks++) {
            const size_t qa = hb + (size_t)(qt*128 + wave*32 + 16*i + l15) * DD + ks*32 + l16*8;
            qfh[i][ks] = *reinterpret_cast<const bf16x8*>(&Qh[qa]);
            qfl[i][ks] = *reinterpret_cast<const bf16x8*>(&Ql[qa]);
        }

    float m_run[2][4], l_run[2][4];
#pragma unroll
    for (int i = 0; i < 2; i++)
#pragma unroll
        for (int r = 0; r < 4; r++) { m_run[i][r] = -3.0e38f; l_run[i][r] = 0.f; }

    f32x4 zero = {0.f, 0.f, 0.f, 0.f};

    // ================= phase 1: online max & sum =================
    for (int kt = 0; kt < 16; kt++) {
#pragma unroll
        for (int p = 0; p < 4; p++) {
            const int row = sr + 32 * p;
            const size_t gk = (size_t)(kt*128 + row) * DD + sc;
            *reinterpret_cast<ushort8*>(&skh[row*LDP + sc]) = *reinterpret_cast<const ushort8*>(&kbh[gk]);
            *reinterpret_cast<ushort8*>(&skl[row*LDP + sc]) = *reinterpret_cast<const ushort8*>(&kbl[gk]);
        }
        __syncthreads();

        f32x4 accs[2][8];
#pragma unroll
        for (int i = 0; i < 2; i++)
#pragma unroll
            for (int j = 0; j < 8; j++) accs[i][j] = zero;

#pragma unroll
        for (int ks = 0; ks < 2; ks++) {
            const int kk = ks*32 + l16*8;
#pragma unroll
            for (int j = 0; j < 8; j++) {
                const int rb = (16*j + l15) * LDP + kk;
                bf16x8 fbh = *reinterpret_cast<const bf16x8*>(&skh[rb]);
                bf16x8 fbl = *reinterpret_cast<const bf16x8*>(&skl[rb]);
#pragma unroll
                for (int i = 0; i < 2; i++) {
                    accs[i][j] = __builtin_amdgcn_mfma_f32_16x16x32_bf16(qfh[i][ks], fbh, accs[i][j], 0, 0, 0);
                    accs[i][j] = __builtin_amdgcn_mfma_f32_16x16x32_bf16(qfh[i][ks], fbl, accs[i][j], 0, 0, 0);
                    accs[i][j] = __builtin_amdgcn_mfma_f32_16x16x32_bf16(qfl[i][ks], fbh, accs[i][j], 0, 0, 0);
                }
            }
        }

#pragma unroll
        for (int i = 0; i < 2; i++)
#pragma unroll
            for (int r = 0; r < 4; r++) {
                float tm = accs[i][0][r];
#pragma unroll
                for (int j = 1; j < 8; j++) tm = fmaxf(tm, accs[i][j][r]);
#pragma unroll
                for (int o = 1; o < 16; o <<= 1) tm = fmaxf(tm, __shfl_xor(tm, o));
                const float mn = fmaxf(m_run[i][r], tm);
                const float c = __builtin_amdgcn_exp2f(m_run[i][r] - mn);
                float ps = 0.f;
#pragma unroll
                for (int j = 0; j < 8; j++) ps += __builtin_amdgcn_exp2f(accs[i][j][r] - mn);
                l_run[i][r] = l_run[i][r] * c + ps;
                m_run[i][r] = mn;
            }
        __syncthreads();
    }

    // finalize: full-row inverse sums
#pragma unroll
    for (int i = 0; i < 2; i++)
#pragma unroll
        for (int r = 0; r < 4; r++) {
            float s = l_run[i][r];
#pragma unroll
            for (int o = 1; o < 16; o <<= 1) s += __shfl_xor(s, o);
            l_run[i][r] = 1.0f / s;
        }

    f32x4 acco[2][4];
#pragma unroll
    for (int i = 0; i < 2; i++)
#pragma unroll
        for (int j = 0; j < 4; j++) acco[i][j] = zero;

    float* wbase = attn + ((size_t)bh * SS + qt*128) * SS;

    // ================= phase 2: recompute, write weights, PV =================
    for (int kt = 0; kt < 16; kt++) {
#pragma unroll
        for (int p = 0; p < 4; p++) {
            const int row = sr + 32 * p;
            const size_t gk = (size_t)(kt*128 + row) * DD + sc;
            *reinterpret_cast<ushort8*>(&skh[row*LDP + sc]) = *reinterpret_cast<const ushort8*>(&kbh[gk]);
            *reinterpret_cast<ushort8*>(&skl[row*LDP + sc]) = *reinterpret_cast<const ushort8*>(&kbl[gk]);
        }
        // stage V^T tile [64 d][128 k]
        {
            const int tv0 = t >> 2;
#pragma unroll
            for (int kk2 = 0; kk2 < 2; kk2++) {
                const int tv = tv0 + kk2*64;
#pragma unroll
                for (int u = 0; u < 2; u++) {
                    const int dbase = (t & 3) * 16 + u * 8;
                    ushort8 v8 = *reinterpret_cast<const ushort8*>(&vbs[(size_t)(kt*128 + tv) * DD + dbase]);
#pragma unroll
                    for (int e = 0; e < 8; e++) svt[(dbase + e)*LDW + tv] = v8[e];
                }
            }
        }
        __syncthreads();

        f32x4 accs[2][8];
#pragma unroll
        for (int i = 0; i < 2; i++)
#pragma unroll
            for (int j = 0; j < 8; j++) accs[i][j] = zero;

#pragma unroll
        for (int ks = 0; ks < 2; ks++) {
            const int kk = ks*32 + l16*8;
#pragma unroll
            for (int j = 0; j < 8; j++) {
                const int rb = (16*j + l15) * LDP + kk;
                bf16x8 fbh = *reinterpret_cast<const bf16x8*>(&skh[rb]);
                bf16x8 fbl = *reinterpret_cast<const bf16x8*>(&skl[rb]);
#pragma unroll
                for (int i = 0; i < 2; i++) {
                    accs[i][j] = __builtin_amdgcn_mfma_f32_16x16x32_bf16(qfh[i][ks], fbh, accs[i][j], 0, 0, 0);
                    accs[i][j] = __builtin_amdgcn_mfma_f32_16x16x32_bf16(qfh[i][ks], fbl, accs[i][j], 0, 0, 0);
                    accs[i][j] = __builtin_amdgcn_mfma_f32_16x16x32_bf16(qfl[i][ks], fbh, accs[i][j], 0, 0, 0);
                }
            }
        }

        // normalized weights: fp32 to global (final output), keep in regs for LDS pass
#pragma unroll
        for (int i = 0; i < 2; i++)
#pragma unroll
            for (int r = 0; r < 4; r++) {
                const float mf = m_run[i][r], iv = l_run[i][r];
                const int row = wave*32 + 16*i + l16*4 + r;
                float* wout = wbase + (size_t)row * SS + kt*128 + l15;
#pragma unroll
                for (int j = 0; j < 8; j++) {
                    const float w = __builtin_amdgcn_exp2f(accs[i][j][r] - mf) * iv;
                    accs[i][j][r] = w;
                    wout[16*j] = w;
                }
            }
        __syncthreads();   // all waves done reading K LDS

        // W bf16 into LDS (overlays K tile)
#pragma unroll
        for (int i = 0; i < 2; i++)
#pragma unroll
            for (int r = 0; r < 4; r++) {
                const int row = wave*32 + 16*i + l16*4 + r;
#pragma unroll
                for (int j = 0; j < 8; j++)
                    wlds[row*LDW + l15 + 16*j] = f2bf(accs[i][j][r]);
            }
        __syncthreads();

        // PV: O += W @ V
#pragma unroll
        for (int ks = 0; ks < 4; ks++) {
            const int kk = ks*32 + l16*8;
            bf16x8 wa[2], vbf[4];
#pragma unroll
            for (int i = 0; i < 2; i++)
                wa[i] = *reinterpret_cast<const bf16x8*>(&wlds[(wave*32 + 16*i + l15)*LDW + kk]);
#pragma unroll
            for (int j = 0; j < 4; j++)
                vbf[j] = *reinterpret_cast<const bf16x8*>(&svt[(16*j + l15)*LDW + kk]);
#pragma unroll
            for (int i = 0; i < 2; i++)
#pragma unroll
                for (int j = 0; j < 4; j++)
                    acco[i][j] = __builtin_amdgcn_mfma_f32_16x16x32_bf16(wa[i], vbf[j], acco[i][j], 0, 0, 0);
        }
        __syncthreads();
    }

    // epilogue: attn_output split-bf16 into [b, s, h*64+d]
    const int b = bh >> 3, h = bh & 7;
#pragma unroll
    for (int i = 0; i < 2; i++)
#pragma unroll
        for (int j = 0; j < 4; j++)
#pragma unroll
            for (int r4 = 0; r4 < 4; r4++) {
                const int srow = qt*128 + wave*32 + 16*i + (l16 << 2) + r4;
                const int col = h*64 + 16*j + l15;
                const size_t idx = ((size_t)b * SS + srow) * (size_t)EE + col;
                const float val = acco[i][j][r4];
                const uint16_t hh = f2bf(val);
                Oh[idx] = hh;
                Ol[idx] = f2bf(val - bf2f(hh));
            }
}

extern "C" void kernel_launch(void* const* d_in, const int* in_sizes, int n_in,
                              void* d_out, int out_size, void* d_ws, size_t ws_size,
                              hipStream_t stream)
{
    const float* x  = (const float*)d_in[0];
    const float* Wq = (const float*)d_in[1];
    const float* bq = (const float*)d_in[2];
    const float* Wk = (const float*)d_in[3];
    const float* bk = (const float*)d_in[4];
    const float* Wv = (const float*)d_in[5];
    const float* bv = (const float*)d_in[6];
    const float* Wo = (const float*)d_in[7];
    const float* bo = (const float*)d_in[8];

    float* outF = (float*)d_out;
    float* attn = outF + (size_t)MM * EE;   // output 1 region (normalized weights)

    const size_t NXE = (size_t)MM * EE;     // 4,194,304
    const size_t NW  = (size_t)EE * EE;     // 262,144
    uint16_t* p = (uint16_t*)d_ws;
    uint16_t* xh    = p;          p += NXE;
    uint16_t* xl    = p;          p += NXE;
    uint16_t* wqkvh = p;          p += 3*NW;
    uint16_t* wqkvl = p;          p += 3*NW;
    uint16_t* woh   = p;          p += NW;
    uint16_t* wol   = p;          p += NW;
    uint16_t* qh    = p;          p += NXE;
    uint16_t* ql    = p;          p += NXE;
    uint16_t* kh    = p;          p += NXE;
    uint16_t* kl    = p;          p += NXE;
    uint16_t* vh    = p;          p += NXE;
    uint16_t* ah    = p;          p += NXE;
    uint16_t* al    = p;          p += NXE;

    split_k<<<(int)((NXE/4 + 255)/256), 256, 0, stream>>>(x,  xh,  xl,  (int)(NXE/4));
    split_k<<<(int)((NW /4 + 255)/256), 256, 0, stream>>>(Wq, wqkvh,        wqkvl,        (int)(NW/4));
    split_k<<<(int)((NW /4 + 255)/256), 256, 0, stream>>>(Wk, wqkvh + NW,   wqkvl + NW,   (int)(NW/4));
    split_k<<<(int)((NW /4 + 255)/256), 256, 0, stream>>>(Wv, wqkvh + 2*NW, wqkvl + 2*NW, (int)(NW/4));
    split_k<<<(int)((NW /4 + 255)/256), 256, 0, stream>>>(Wo, woh, wol, (int)(NW/4));

    // Q scaled by 0.125*log2(e): scores land in log2 units -> softmax uses exp2 directly
    const float qscale = 0.125f * 1.44269504088896340736f;
    gemm_qkv<<<dim3(MM/128, (3*EE)/128), 256, 0, stream>>>(
        xh, xl, wqkvh, wqkvl, bq, bk, bv, qscale, qh, ql, kh, kl, vh);

    attn_fused<<<dim3(SS/128, NB*NH), 256, 0, stream>>>(qh, ql, kh, kl, vh, attn, ah, al);

    gemm_out<<<dim3(MM/64, EE/128), 256, 0, stream>>>(ah, al, woh, wol, bo, outF);
}

// Round 6
// 278.972 us; speedup vs baseline: 1.3933x; 1.1992x over previous
//
#include <hip/hip_runtime.h>
#include <stdint.h>

#define NB 4
#define NH 8
#define SS 2048
#define EE 512
#define DD 64
#define MM (NB*SS)      // 8192
#define LDP 72          // padded LDS row (bf16 elems) for K-dim-64 tiles
#define LDW 136         // padded LDS row for 128-wide W / V^T tiles

typedef __attribute__((ext_vector_type(8))) __bf16 bf16x8;
typedef __attribute__((ext_vector_type(8))) unsigned short ushort8;
typedef __attribute__((ext_vector_type(4))) unsigned short ushort4v;
typedef __attribute__((ext_vector_type(4))) float f32x4;

__device__ __forceinline__ uint16_t f2bf(float f) {
    union { float f; uint32_t u; } v; v.f = f;
    return (uint16_t)((v.u + 0x7fffu + ((v.u >> 16) & 1u)) >> 16);   // RNE
}
__device__ __forceinline__ float bf2f(uint16_t h) {
    union { uint32_t u; float f; } v; v.u = ((uint32_t)h) << 16;
    return v.f;
}

// ---------------- merged split: x + Wq/Wk/Wv/Wo -> bf16 hi/lo ----------------
__global__ __launch_bounds__(256) void split_all(
        const float* __restrict__ x,  const float* __restrict__ Wq,
        const float* __restrict__ Wk, const float* __restrict__ Wv,
        const float* __restrict__ Wo,
        uint16_t* __restrict__ xh, uint16_t* __restrict__ xl,
        uint16_t* __restrict__ wqkvh, uint16_t* __restrict__ wqkvl,
        uint16_t* __restrict__ woh, uint16_t* __restrict__ wol)
{
    const int tid = threadIdx.x;
    int b = blockIdx.x;
    const float* src; uint16_t* dh; uint16_t* dl; int i;
    if (b < 4096) { src = x; dh = xh; dl = xl; i = b*256 + tid; }
    else {
        b -= 4096;
        const int seg = b >> 8;                 // 0..3
        i = (b & 255)*256 + tid;
        src = (seg == 0) ? Wq : (seg == 1) ? Wk : (seg == 2) ? Wv : Wo;
        if (seg < 3) { dh = wqkvh + (size_t)seg*262144; dl = wqkvl + (size_t)seg*262144; }
        else         { dh = woh; dl = wol; }
    }
    f32x4 v = reinterpret_cast<const f32x4*>(src)[i];
    ushort4v h, l;
#pragma unroll
    for (int j = 0; j < 4; j++) {
        uint16_t hh = f2bf(v[j]);
        h[j] = hh;
        l[j] = f2bf(v[j] - bf2f(hh));
    }
    reinterpret_cast<ushort4v*>(dh)[i] = h;
    reinterpret_cast<ushort4v*>(dl)[i] = l;
}

// ---------------- merged QKV projection, BM=64: [8192x512] @ [1536x512]^T ----------------
__global__ __launch_bounds__(256, 2)
void gemm_qkv(const uint16_t* __restrict__ Ah, const uint16_t* __restrict__ Al,
              const uint16_t* __restrict__ Bh, const uint16_t* __restrict__ Bl,
              const float* __restrict__ bq, const float* __restrict__ bk,
              const float* __restrict__ bv, float qscale,
              uint16_t* __restrict__ qh, uint16_t* __restrict__ ql,
              uint16_t* __restrict__ kh, uint16_t* __restrict__ kl,
              uint16_t* __restrict__ vh)
{
    __shared__ uint16_t sAh[64*LDP], sAl[64*LDP], sBh[128*LDP], sBl[128*LDP];
    const int t = threadIdx.x;
    const int lane = t & 63;
    const int wave = t >> 6;
    const int m0 = blockIdx.x * 64;
    const int n0 = blockIdx.y * 128;

    f32x4 zero = {0.f, 0.f, 0.f, 0.f};
    f32x4 acc[2][4];
#pragma unroll
    for (int i = 0; i < 2; i++)
#pragma unroll
        for (int j = 0; j < 4; j++) acc[i][j] = zero;

    const int sr = t >> 3;        // 0..31
    const int sc = (t & 7) * 8;   // 0..56

    for (int k0 = 0; k0 < EE; k0 += 64) {
#pragma unroll
        for (int p = 0; p < 2; p++) {
            const int row = sr + 32 * p;
            const size_t ga = (size_t)(m0 + row) * EE + k0 + sc;
            *reinterpret_cast<ushort8*>(&sAh[row*LDP + sc]) = *reinterpret_cast<const ushort8*>(&Ah[ga]);
            *reinterpret_cast<ushort8*>(&sAl[row*LDP + sc]) = *reinterpret_cast<const ushort8*>(&Al[ga]);
        }
#pragma unroll
        for (int p = 0; p < 4; p++) {
            const int row = sr + 32 * p;
            const size_t gb = (size_t)(n0 + row) * EE + k0 + sc;
            *reinterpret_cast<ushort8*>(&sBh[row*LDP + sc]) = *reinterpret_cast<const ushort8*>(&Bh[gb]);
            *reinterpret_cast<ushort8*>(&sBl[row*LDP + sc]) = *reinterpret_cast<const ushort8*>(&Bl[gb]);
        }
        __syncthreads();
        const int mw = (wave >> 1) * 32;
        const int nw = (wave & 1) * 64;
#pragma unroll
        for (int ks = 0; ks < 2; ks++) {
            const int kk = ks*32 + (lane >> 4) * 8;
            bf16x8 fah[2], fal[2], fbh[4], fbl[4];
#pragma unroll
            for (int i = 0; i < 2; i++) {
                const int ra = (mw + 16*i + (lane & 15)) * LDP + kk;
                fah[i] = *reinterpret_cast<const bf16x8*>(&sAh[ra]);
                fal[i] = *reinterpret_cast<const bf16x8*>(&sAl[ra]);
            }
#pragma unroll
            for (int j = 0; j < 4; j++) {
                const int rb = (nw + 16*j + (lane & 15)) * LDP + kk;
                fbh[j] = *reinterpret_cast<const bf16x8*>(&sBh[rb]);
                fbl[j] = *reinterpret_cast<const bf16x8*>(&sBl[rb]);
            }
#pragma unroll
            for (int i = 0; i < 2; i++)
#pragma unroll
                for (int j = 0; j < 4; j++) {
                    acc[i][j] = __builtin_amdgcn_mfma_f32_16x16x32_bf16(fah[i], fbh[j], acc[i][j], 0, 0, 0);
                    acc[i][j] = __builtin_amdgcn_mfma_f32_16x16x32_bf16(fah[i], fbl[j], acc[i][j], 0, 0, 0);
                    acc[i][j] = __builtin_amdgcn_mfma_f32_16x16x32_bf16(fal[i], fbh[j], acc[i][j], 0, 0, 0);
                }
        }
        __syncthreads();
    }

    const int mw = (wave >> 1) * 32;
    const int nw = (wave & 1) * 64;
#pragma unroll
    for (int j = 0; j < 4; j++) {
        const int col = n0 + nw + 16*j + (lane & 15);   // 0..1535
        const int seg = col >> 9;                        // 0=Q 1=K 2=V
        const int c   = col & 511;
        const float bias = (seg == 0 ? bq : (seg == 1 ? bk : bv))[c];
        const float scale = (seg == 0) ? qscale : 1.0f;
        const int h = c >> 6, d = c & 63;
#pragma unroll
        for (int i = 0; i < 2; i++) {
            const int rowb = m0 + mw + 16*i + ((lane >> 4) << 2);
#pragma unroll
            for (int r4 = 0; r4 < 4; r4++) {
                const int m = rowb + r4;
                const float val = (acc[i][j][r4] + bias) * scale;
                const int bb = m >> 11, s = m & (SS-1);
                const size_t idx = (((size_t)(bb*NH + h)) * SS + s) * DD + d;
                const uint16_t hi = f2bf(val);
                if (seg == 0)      { qh[idx] = hi; ql[idx] = f2bf(val - bf2f(hi)); }
                else if (seg == 1) { kh[idx] = hi; kl[idx] = f2bf(val - bf2f(hi)); }
                else               { vh[idx] = hi; }
            }
        }
    }
}

// ---------------- out-projection: [8192x512] @ [512x512]^T + bo, fp32 out, BM=64 ----------------
__global__ __launch_bounds__(256, 2)
void gemm_out(const uint16_t* __restrict__ Ah, const uint16_t* __restrict__ Al,
              const uint16_t* __restrict__ Bh, const uint16_t* __restrict__ Bl,
              const float* __restrict__ bo, float* __restrict__ Of)
{
    __shared__ uint16_t sAh[64*LDP], sAl[64*LDP], sBh[128*LDP], sBl[128*LDP];
    const int t = threadIdx.x;
    const int lane = t & 63;
    const int wave = t >> 6;
    const int m0 = blockIdx.x * 64;
    const int n0 = blockIdx.y * 128;

    f32x4 zero = {0.f, 0.f, 0.f, 0.f};
    f32x4 acc[2][4];
#pragma unroll
    for (int i = 0; i < 2; i++)
#pragma unroll
        for (int j = 0; j < 4; j++) acc[i][j] = zero;

    const int sr = t >> 3;        // 0..31
    const int sc = (t & 7) * 8;   // 0..56

    for (int k0 = 0; k0 < EE; k0 += 64) {
#pragma unroll
        for (int p = 0; p < 2; p++) {
            const int row = sr + 32 * p;
            const size_t ga = (size_t)(m0 + row) * EE + k0 + sc;
            *reinterpret_cast<ushort8*>(&sAh[row*LDP + sc]) = *reinterpret_cast<const ushort8*>(&Ah[ga]);
            *reinterpret_cast<ushort8*>(&sAl[row*LDP + sc]) = *reinterpret_cast<const ushort8*>(&Al[ga]);
        }
#pragma unroll
        for (int p = 0; p < 4; p++) {
            const int row = sr + 32 * p;
            const size_t gb = (size_t)(n0 + row) * EE + k0 + sc;
            *reinterpret_cast<ushort8*>(&sBh[row*LDP + sc]) = *reinterpret_cast<const ushort8*>(&Bh[gb]);
            *reinterpret_cast<ushort8*>(&sBl[row*LDP + sc]) = *reinterpret_cast<const ushort8*>(&Bl[gb]);
        }
        __syncthreads();
        const int mw = (wave >> 1) * 32;
        const int nw = (wave & 1) * 64;
#pragma unroll
        for (int ks = 0; ks < 2; ks++) {
            const int kk = ks*32 + (lane >> 4) * 8;
            bf16x8 fah[2], fal[2], fbh[4], fbl[4];
#pragma unroll
            for (int i = 0; i < 2; i++) {
                const int ra = (mw + 16*i + (lane & 15)) * LDP + kk;
                fah[i] = *reinterpret_cast<const bf16x8*>(&sAh[ra]);
                fal[i] = *reinterpret_cast<const bf16x8*>(&sAl[ra]);
            }
#pragma unroll
            for (int j = 0; j < 4; j++) {
                const int rb = (nw + 16*j + (lane & 15)) * LDP + kk;
                fbh[j] = *reinterpret_cast<const bf16x8*>(&sBh[rb]);
                fbl[j] = *reinterpret_cast<const bf16x8*>(&sBl[rb]);
            }
#pragma unroll
            for (int i = 0; i < 2; i++)
#pragma unroll
                for (int j = 0; j < 4; j++) {
                    acc[i][j] = __builtin_amdgcn_mfma_f32_16x16x32_bf16(fah[i], fbh[j], acc[i][j], 0, 0, 0);
                    acc[i][j] = __builtin_amdgcn_mfma_f32_16x16x32_bf16(fah[i], fbl[j], acc[i][j], 0, 0, 0);
                    acc[i][j] = __builtin_amdgcn_mfma_f32_16x16x32_bf16(fal[i], fbh[j], acc[i][j], 0, 0, 0);
                }
        }
        __syncthreads();
    }

    const int mw = (wave >> 1) * 32;
    const int nw = (wave & 1) * 64;
#pragma unroll
    for (int j = 0; j < 4; j++) {
        const int col = n0 + nw + 16*j + (lane & 15);
        const float bv = bo[col];
#pragma unroll
        for (int i = 0; i < 2; i++) {
            const int rowb = m0 + mw + 16*i + ((lane >> 4) << 2);
#pragma unroll
            for (int r4 = 0; r4 < 4; r4++)
                Of[(size_t)(rowb + r4) * EE + col] = acc[i][j][r4] + bv;
        }
    }
}

// ---------------- fused flash attention, sum-only softmax (no max pass) ----------------
// Scores in log2 units (Q pre-scaled by 0.125*log2e). exp2 is fp32-safe unshifted:
// score sigma ~0.5 log2-units, theoretical worst |s| << 120.
__global__ __launch_bounds__(256, 2)
void attn_fused(const uint16_t* __restrict__ Qh, const uint16_t* __restrict__ Ql,
                const uint16_t* __restrict__ Kh, const uint16_t* __restrict__ Kl,
                const uint16_t* __restrict__ Vh,
                float* __restrict__ attn,
                uint16_t* __restrict__ Oh, uint16_t* __restrict__ Ol)
{
    __shared__ __align__(16) uint16_t smem[36864];   // 73728 B -> 2 blocks/CU
    uint16_t* bufA = smem;          // K tile: hi [128][72] @0, lo @+9216 | phase2 W overlay [128][136]
    uint16_t* bufB = smem + 18432;  // phase1 dbuf partner | phase2 V^T [64][136]

    const int t = threadIdx.x, lane = t & 63, wave = t >> 6;
    const int qt = blockIdx.x, bh = blockIdx.y;
    const size_t hb = (size_t)bh * SS * DD;
    const uint16_t* kbh = Kh + hb;
    const uint16_t* kbl = Kl + hb;
    const uint16_t* vbs = Vh + hb;

    const int l15 = lane & 15;
    const int l16 = lane >> 4;
    const int sr = t >> 3;        // 0..31
    const int sc = (t & 7) * 8;   // 0..56

    // ---- K staging regs (global->reg->LDS) ----
    ushort8 krh[4], krl[4];
    auto kload = [&](int kt) {
#pragma unroll
        for (int p = 0; p < 4; p++) {
            const size_t g = (size_t)(kt*128 + sr + 32*p) * DD + sc;
            krh[p] = *reinterpret_cast<const ushort8*>(&kbh[g]);
            krl[p] = *reinterpret_cast<const ushort8*>(&kbl[g]);
        }
    };
    auto kwrite = [&](uint16_t* buf) {
#pragma unroll
        for (int p = 0; p < 4; p++) {
            const int o = (sr + 32*p)*LDP + sc;
            *reinterpret_cast<ushort8*>(&buf[o]) = krh[p];
            *reinterpret_cast<ushort8*>(&buf[9216 + o]) = krl[p];
        }
    };

    // ---- Q fragments in registers (persistent) ----
    bf16x8 qfh[2][2], qfl[2][2];
#pragma unroll
    for (int i = 0; i < 2; i++)
#pragma unroll
        for (int ks = 0; ks < 2; ks++) {
            const size_t qa = hb + (size_t)(qt*128 + wave*32 + 16*i + l15) * DD + ks*32 + l16*8;
            qfh[i][ks] = *reinterpret_cast<const bf16x8*>(&Qh[qa]);
            qfl[i][ks] = *reinterpret_cast<const bf16x8*>(&Ql[qa]);
        }

    f32x4 zero = {0.f, 0.f, 0.f, 0.f};
    f32x4 lsum[2] = {zero, zero};

    // ================= phase 1: row sums of exp2(scores) =================
    kload(0);
#pragma unroll 1
    for (int kt = 0; kt < 16; kt++) {
        uint16_t* buf = (kt & 1) ? bufB : bufA;
        kwrite(buf);
        if (kt < 15) kload(kt + 1);
        __syncthreads();

        f32x4 accs[2][8];
#pragma unroll
        for (int i = 0; i < 2; i++)
#pragma unroll
            for (int j = 0; j < 8; j++) accs[i][j] = zero;

#pragma unroll
        for (int ks = 0; ks < 2; ks++) {
            const int kk = ks*32 + l16*8;
#pragma unroll
            for (int j = 0; j < 8; j++) {
                const int rb = (16*j + l15) * LDP + kk;
                bf16x8 fbh = *reinterpret_cast<const bf16x8*>(&buf[rb]);
                bf16x8 fbl = *reinterpret_cast<const bf16x8*>(&buf[9216 + rb]);
#pragma unroll
                for (int i = 0; i < 2; i++) {
                    accs[i][j] = __builtin_amdgcn_mfma_f32_16x16x32_bf16(qfh[i][ks], fbh, accs[i][j], 0, 0, 0);
                    accs[i][j] = __builtin_amdgcn_mfma_f32_16x16x32_bf16(qfh[i][ks], fbl, accs[i][j], 0, 0, 0);
                    accs[i][j] = __builtin_amdgcn_mfma_f32_16x16x32_bf16(qfl[i][ks], fbh, accs[i][j], 0, 0, 0);
                }
            }
        }

#pragma unroll
        for (int i = 0; i < 2; i++)
#pragma unroll
            for (int j = 0; j < 8; j++)
#pragma unroll
                for (int r = 0; r < 4; r++)
                    lsum[i][r] += __builtin_amdgcn_exp2f(accs[i][j][r]);
    }

    // finalize: reduce over the 16-lane row group, invert
    f32x4 iv[2];
#pragma unroll
    for (int i = 0; i < 2; i++)
#pragma unroll
        for (int r = 0; r < 4; r++) {
            float s = lsum[i][r];
#pragma unroll
            for (int o = 1; o < 16; o <<= 1) s += __shfl_xor(s, o);
            iv[i][r] = 1.0f / s;
        }

    f32x4 acco[2][4];
#pragma unroll
    for (int i = 0; i < 2; i++)
#pragma unroll
        for (int j = 0; j < 4; j++) acco[i][j] = zero;

    float* wbase = attn + ((size_t)bh * SS + qt*128) * SS;

    // ---- V staging: pair-packed b32 writes (conflict-free) ----
    const int pk = t & 63;             // k-pair index (k = 2pk, 2pk+1)
    const int dbase = (t >> 6) * 16;   // d-quarter
    ushort8 vr[2][2];
    auto vload = [&](int kt) {
#pragma unroll
        for (int u = 0; u < 2; u++)
#pragma unroll
            for (int s = 0; s < 2; s++)
                vr[u][s] = *reinterpret_cast<const ushort8*>(
                    &vbs[(size_t)(kt*128 + 2*pk + s) * DD + dbase + u*8]);
    };
    auto vwrite = [&]() {
#pragma unroll
        for (int u = 0; u < 2; u++)
#pragma unroll
            for (int e = 0; e < 8; e++) {
                const int d = dbase + u*8 + e;
                const uint32_t pack = (uint32_t)(unsigned short)vr[u][0][e]
                                    | ((uint32_t)(unsigned short)vr[u][1][e] << 16);
                *reinterpret_cast<uint32_t*>(&bufB[d*LDW + 2*pk]) = pack;
            }
    };

    __syncthreads();   // phase boundary: all phase-1 reads of bufB done

    // ================= phase 2: recompute, write weights, PV =================
    kload(0); vload(0);
#pragma unroll 1
    for (int kt = 0; kt < 16; kt++) {
        kwrite(bufA);
        vwrite();
        __syncthreads();                       // bar1: K/V staged

        f32x4 accs[2][8];
#pragma unroll
        for (int i = 0; i < 2; i++)
#pragma unroll
            for (int j = 0; j < 8; j++) accs[i][j] = zero;
#pragma unroll
        for (int ks = 0; ks < 2; ks++) {
            const int kk = ks*32 + l16*8;
#pragma unroll
            for (int j = 0; j < 8; j++) {
                const int rb = (16*j + l15) * LDP + kk;
                bf16x8 fbh = *reinterpret_cast<const bf16x8*>(&bufA[rb]);
                bf16x8 fbl = *reinterpret_cast<const bf16x8*>(&bufA[9216 + rb]);
#pragma unroll
                for (int i = 0; i < 2; i++) {
                    accs[i][j] = __builtin_amdgcn_mfma_f32_16x16x32_bf16(qfh[i][ks], fbh, accs[i][j], 0, 0, 0);
                    accs[i][j] = __builtin_amdgcn_mfma_f32_16x16x32_bf16(qfh[i][ks], fbl, accs[i][j], 0, 0, 0);
                    accs[i][j] = __builtin_amdgcn_mfma_f32_16x16x32_bf16(qfl[i][ks], fbh, accs[i][j], 0, 0, 0);
                }
            }
        }

        // prefetch next tile's K/V while VALU works (T14)
        if (kt < 15) { kload(kt + 1); vload(kt + 1); }

        // normalize: w = exp2(s) * inv_sum (no max shift)
#pragma unroll
        for (int i = 0; i < 2; i++)
#pragma unroll
            for (int j = 0; j < 8; j++)
#pragma unroll
                for (int r = 0; r < 4; r++)
                    accs[i][j][r] = __builtin_amdgcn_exp2f(accs[i][j][r]) * iv[i][r];

        // weight stores (final output 1, fp32)
#pragma unroll
        for (int i = 0; i < 2; i++)
#pragma unroll
            for (int r = 0; r < 4; r++) {
                const int row = wave*32 + 16*i + l16*4 + r;
                float* wout = wbase + (size_t)row * SS + kt*128 + l15;
#pragma unroll
                for (int j = 0; j < 8; j++) wout[16*j] = accs[i][j][r];
            }
        __syncthreads();                       // bar2: all K reads done

        // W bf16 -> bufA overlay
#pragma unroll
        for (int i = 0; i < 2; i++)
#pragma unroll
            for (int r = 0; r < 4; r++) {
                const int row = wave*32 + 16*i + l16*4 + r;
#pragma unroll
                for (int j = 0; j < 8; j++)
                    bufA[row*LDW + l15 + 16*j] = f2bf(accs[i][j][r]);
            }
        __syncthreads();                       // bar3: W/V visible

        // PV: O += W @ V
#pragma unroll
        for (int ks = 0; ks < 4; ks++) {
            const int kk = ks*32 + l16*8;
            bf16x8 wa[2], vbf[4];
#pragma unroll
            for (int i = 0; i < 2; i++)
                wa[i] = *reinterpret_cast<const bf16x8*>(&bufA[(wave*32 + 16*i + l15)*LDW + kk]);
#pragma unroll
            for (int j = 0; j < 4; j++)
                vbf[j] = *reinterpret_cast<const bf16x8*>(&bufB[(16*j + l15)*LDW + kk]);
#pragma unroll
            for (int i = 0; i < 2; i++)
#pragma unroll
                for (int j = 0; j < 4; j++)
                    acco[i][j] = __builtin_amdgcn_mfma_f32_16x16x32_bf16(wa[i], vbf[j], acco[i][j], 0, 0, 0);
        }
        __syncthreads();                       // bar4: PV reads done before next staging
    }

    // epilogue: attn_output split-bf16 into [b, s, h*64+d]
    const int b = bh >> 3, h = bh & 7;
#pragma unroll
    for (int i = 0; i < 2; i++)
#pragma unroll
        for (int j = 0; j < 4; j++)
#pragma unroll
            for (int r4 = 0; r4 < 4; r4++) {
                const int srow = qt*128 + wave*32 + 16*i + (l16 << 2) + r4;
                const int col = h*64 + 16*j + l15;
                const size_t idx = ((size_t)b * SS + srow) * (size_t)EE + col;
                const float val = acco[i][j][r4];
                const uint16_t hh = f2bf(val);
                Oh[idx] = hh;
                Ol[idx] = f2bf(val - bf2f(hh));
            }
}

extern "C" void kernel_launch(void* const* d_in, const int* in_sizes, int n_in,
                              void* d_out, int out_size, void* d_ws, size_t ws_size,
                              hipStream_t stream)
{
    const float* x  = (const float*)d_in[0];
    const float* Wq = (const float*)d_in[1];
    const float* bq = (const float*)d_in[2];
    const float* Wk = (const float*)d_in[3];
    const float* bk = (const float*)d_in[4];
    const float* Wv = (const float*)d_in[5];
    const float* bv = (const float*)d_in[6];
    const float* Wo = (const float*)d_in[7];
    const float* bo = (const float*)d_in[8];

    float* outF = (float*)d_out;
    float* attn = outF + (size_t)MM * EE;   // output 1 region (normalized weights)

    const size_t NXE = (size_t)MM * EE;     // 4,194,304
    const size_t NW  = (size_t)EE * EE;     // 262,144
    uint16_t* p = (uint16_t*)d_ws;
    uint16_t* xh    = p;          p += NXE;
    uint16_t* xl    = p;          p += NXE;
    uint16_t* wqkvh = p;          p += 3*NW;
    uint16_t* wqkvl = p;          p += 3*NW;
    uint16_t* woh   = p;          p += NW;
    uint16_t* wol   = p;          p += NW;
    uint16_t* qh    = p;          p += NXE;
    uint16_t* ql    = p;          p += NXE;
    uint16_t* kh    = p;          p += NXE;
    uint16_t* kl    = p;          p += NXE;
    uint16_t* vh    = p;          p += NXE;
    uint16_t* ah    = p;          p += NXE;
    uint16_t* al    = p;          p += NXE;

    split_all<<<4096 + 4*256, 256, 0, stream>>>(x, Wq, Wk, Wv, Wo,
                                                xh, xl, wqkvh, wqkvl, woh, wol);

    // Q scaled by 0.125*log2(e): scores land in log2 units -> softmax uses exp2 directly
    const float qscale = 0.125f * 1.44269504088896340736f;
    gemm_qkv<<<dim3(MM/64, (3*EE)/128), 256, 0, stream>>>(
        xh, xl, wqkvh, wqkvl, bq, bk, bv, qscale, qh, ql, kh, kl, vh);

    attn_fused<<<dim3(SS/128, NB*NH), 256, 0, stream>>>(qh, ql, kh, kl, vh, attn, ah, al);

    gemm_out<<<dim3(MM/64, EE/128), 256, 0, stream>>>(ah, al, woh, wol, bo, outF);
}

// Round 7
// 257.266 us; speedup vs baseline: 1.5109x; 1.0844x over previous
//
#include <hip/hip_runtime.h>
#include <stdint.h>

#define NB 4
#define NH 8
#define SS 2048
#define EE 512
#define DD 64
#define MM (NB*SS)      // 8192
#define LDP 72          // padded LDS row (bf16 elems) for K-dim-64 tiles
#define LDW 136         // padded LDS row for 128-wide W / V^T tiles

typedef __attribute__((ext_vector_type(8))) __bf16 bf16x8;
typedef __attribute__((ext_vector_type(8))) unsigned short ushort8;
typedef __attribute__((ext_vector_type(4))) unsigned short ushort4v;
typedef __attribute__((ext_vector_type(4))) float f32x4;

__device__ __forceinline__ uint16_t f2bf(float f) {
    union { float f; uint32_t u; } v; v.f = f;
    return (uint16_t)((v.u + 0x7fffu + ((v.u >> 16) & 1u)) >> 16);   // RNE
}
__device__ __forceinline__ float bf2f(uint16_t h) {
    union { uint32_t u; float f; } v; v.u = ((uint32_t)h) << 16;
    return v.f;
}

// ---------------- merged split: x + Wq/Wk/Wv/Wo -> bf16 hi/lo ----------------
__global__ __launch_bounds__(256) void split_all(
        const float* __restrict__ x,  const float* __restrict__ Wq,
        const float* __restrict__ Wk, const float* __restrict__ Wv,
        const float* __restrict__ Wo,
        uint16_t* __restrict__ xh, uint16_t* __restrict__ xl,
        uint16_t* __restrict__ wqkvh, uint16_t* __restrict__ wqkvl,
        uint16_t* __restrict__ woh, uint16_t* __restrict__ wol)
{
    const int tid = threadIdx.x;
    int b = blockIdx.x;
    const float* src; uint16_t* dh; uint16_t* dl; int i;
    if (b < 4096) { src = x; dh = xh; dl = xl; i = b*256 + tid; }
    else {
        b -= 4096;
        const int seg = b >> 8;                 // 0..3
        i = (b & 255)*256 + tid;
        src = (seg == 0) ? Wq : (seg == 1) ? Wk : (seg == 2) ? Wv : Wo;
        if (seg < 3) { dh = wqkvh + (size_t)seg*262144; dl = wqkvl + (size_t)seg*262144; }
        else         { dh = woh; dl = wol; }
    }
    f32x4 v = reinterpret_cast<const f32x4*>(src)[i];
    ushort4v h, l;
#pragma unroll
    for (int j = 0; j < 4; j++) {
        uint16_t hh = f2bf(v[j]);
        h[j] = hh;
        l[j] = f2bf(v[j] - bf2f(hh));
    }
    reinterpret_cast<ushort4v*>(dh)[i] = h;
    reinterpret_cast<ushort4v*>(dl)[i] = l;
}

// ---------------- merged QKV projection, BM=64: [8192x512] @ [1536x512]^T ----------------
__global__ __launch_bounds__(256, 2)
void gemm_qkv(const uint16_t* __restrict__ Ah, const uint16_t* __restrict__ Al,
              const uint16_t* __restrict__ Bh, const uint16_t* __restrict__ Bl,
              const float* __restrict__ bq, const float* __restrict__ bk,
              const float* __restrict__ bv, float qscale,
              uint16_t* __restrict__ qh, uint16_t* __restrict__ ql,
              uint16_t* __restrict__ kh, uint16_t* __restrict__ kl,
              uint16_t* __restrict__ vh)
{
    __shared__ uint16_t sAh[64*LDP], sAl[64*LDP], sBh[128*LDP], sBl[128*LDP];
    const int t = threadIdx.x;
    const int lane = t & 63;
    const int wave = t >> 6;
    const int m0 = blockIdx.x * 64;
    const int n0 = blockIdx.y * 128;

    f32x4 zero = {0.f, 0.f, 0.f, 0.f};
    f32x4 acc[2][4];
#pragma unroll
    for (int i = 0; i < 2; i++)
#pragma unroll
        for (int j = 0; j < 4; j++) acc[i][j] = zero;

    const int sr = t >> 3;        // 0..31
    const int sc = (t & 7) * 8;   // 0..56

    for (int k0 = 0; k0 < EE; k0 += 64) {
#pragma unroll
        for (int p = 0; p < 2; p++) {
            const int row = sr + 32 * p;
            const size_t ga = (size_t)(m0 + row) * EE + k0 + sc;
            *reinterpret_cast<ushort8*>(&sAh[row*LDP + sc]) = *reinterpret_cast<const ushort8*>(&Ah[ga]);
            *reinterpret_cast<ushort8*>(&sAl[row*LDP + sc]) = *reinterpret_cast<const ushort8*>(&Al[ga]);
        }
#pragma unroll
        for (int p = 0; p < 4; p++) {
            const int row = sr + 32 * p;
            const size_t gb = (size_t)(n0 + row) * EE + k0 + sc;
            *reinterpret_cast<ushort8*>(&sBh[row*LDP + sc]) = *reinterpret_cast<const ushort8*>(&Bh[gb]);
            *reinterpret_cast<ushort8*>(&sBl[row*LDP + sc]) = *reinterpret_cast<const ushort8*>(&Bl[gb]);
        }
        __syncthreads();
        const int mw = (wave >> 1) * 32;
        const int nw = (wave & 1) * 64;
#pragma unroll
        for (int ks = 0; ks < 2; ks++) {
            const int kk = ks*32 + (lane >> 4) * 8;
            bf16x8 fah[2], fal[2], fbh[4], fbl[4];
#pragma unroll
            for (int i = 0; i < 2; i++) {
                const int ra = (mw + 16*i + (lane & 15)) * LDP + kk;
                fah[i] = *reinterpret_cast<const bf16x8*>(&sAh[ra]);
                fal[i] = *reinterpret_cast<const bf16x8*>(&sAl[ra]);
            }
#pragma unroll
            for (int j = 0; j < 4; j++) {
                const int rb = (nw + 16*j + (lane & 15)) * LDP + kk;
                fbh[j] = *reinterpret_cast<const bf16x8*>(&sBh[rb]);
                fbl[j] = *reinterpret_cast<const bf16x8*>(&sBl[rb]);
            }
#pragma unroll
            for (int i = 0; i < 2; i++)
#pragma unroll
                for (int j = 0; j < 4; j++) {
                    acc[i][j] = __builtin_amdgcn_mfma_f32_16x16x32_bf16(fah[i], fbh[j], acc[i][j], 0, 0, 0);
                    acc[i][j] = __builtin_amdgcn_mfma_f32_16x16x32_bf16(fah[i], fbl[j], acc[i][j], 0, 0, 0);
                    acc[i][j] = __builtin_amdgcn_mfma_f32_16x16x32_bf16(fal[i], fbh[j], acc[i][j], 0, 0, 0);
                }
        }
        __syncthreads();
    }

    const int mw = (wave >> 1) * 32;
    const int nw = (wave & 1) * 64;
#pragma unroll
    for (int j = 0; j < 4; j++) {
        const int col = n0 + nw + 16*j + (lane & 15);   // 0..1535
        const int seg = col >> 9;                        // 0=Q 1=K 2=V
        const int c   = col & 511;
        const float bias = (seg == 0 ? bq : (seg == 1 ? bk : bv))[c];
        const float scale = (seg == 0) ? qscale : 1.0f;
        const int h = c >> 6, d = c & 63;
#pragma unroll
        for (int i = 0; i < 2; i++) {
            const int rowb = m0 + mw + 16*i + ((lane >> 4) << 2);
#pragma unroll
            for (int r4 = 0; r4 < 4; r4++) {
                const int m = rowb + r4;
                const float val = (acc[i][j][r4] + bias) * scale;
                const int bb = m >> 11, s = m & (SS-1);
                const size_t idx = (((size_t)(bb*NH + h)) * SS + s) * DD + d;
                const uint16_t hi = f2bf(val);
                if (seg == 0)      { qh[idx] = hi; ql[idx] = f2bf(val - bf2f(hi)); }
                else if (seg == 1) { kh[idx] = hi; kl[idx] = f2bf(val - bf2f(hi)); }
                else               { vh[idx] = hi; }
            }
        }
    }
}

// ---------------- out-projection: [8192x512] @ [512x512]^T + bo, fp32 out, BM=64 ----------------
__global__ __launch_bounds__(256, 2)
void gemm_out(const uint16_t* __restrict__ Ah, const uint16_t* __restrict__ Al,
              const uint16_t* __restrict__ Bh, const uint16_t* __restrict__ Bl,
              const float* __restrict__ bo, float* __restrict__ Of)
{
    __shared__ uint16_t sAh[64*LDP], sAl[64*LDP], sBh[128*LDP], sBl[128*LDP];
    const int t = threadIdx.x;
    const int lane = t & 63;
    const int wave = t >> 6;
    const int m0 = blockIdx.x * 64;
    const int n0 = blockIdx.y * 128;

    f32x4 zero = {0.f, 0.f, 0.f, 0.f};
    f32x4 acc[2][4];
#pragma unroll
    for (int i = 0; i < 2; i++)
#pragma unroll
        for (int j = 0; j < 4; j++) acc[i][j] = zero;

    const int sr = t >> 3;        // 0..31
    const int sc = (t & 7) * 8;   // 0..56

    for (int k0 = 0; k0 < EE; k0 += 64) {
#pragma unroll
        for (int p = 0; p < 2; p++) {
            const int row = sr + 32 * p;
            const size_t ga = (size_t)(m0 + row) * EE + k0 + sc;
            *reinterpret_cast<ushort8*>(&sAh[row*LDP + sc]) = *reinterpret_cast<const ushort8*>(&Ah[ga]);
            *reinterpret_cast<ushort8*>(&sAl[row*LDP + sc]) = *reinterpret_cast<const ushort8*>(&Al[ga]);
        }
#pragma unroll
        for (int p = 0; p < 4; p++) {
            const int row = sr + 32 * p;
            const size_t gb = (size_t)(n0 + row) * EE + k0 + sc;
            *reinterpret_cast<ushort8*>(&sBh[row*LDP + sc]) = *reinterpret_cast<const ushort8*>(&Bh[gb]);
            *reinterpret_cast<ushort8*>(&sBl[row*LDP + sc]) = *reinterpret_cast<const ushort8*>(&Bl[gb]);
        }
        __syncthreads();
        const int mw = (wave >> 1) * 32;
        const int nw = (wave & 1) * 64;
#pragma unroll
        for (int ks = 0; ks < 2; ks++) {
            const int kk = ks*32 + (lane >> 4) * 8;
            bf16x8 fah[2], fal[2], fbh[4], fbl[4];
#pragma unroll
            for (int i = 0; i < 2; i++) {
                const int ra = (mw + 16*i + (lane & 15)) * LDP + kk;
                fah[i] = *reinterpret_cast<const bf16x8*>(&sAh[ra]);
                fal[i] = *reinterpret_cast<const bf16x8*>(&sAl[ra]);
            }
#pragma unroll
            for (int j = 0; j < 4; j++) {
                const int rb = (nw + 16*j + (lane & 15)) * LDP + kk;
                fbh[j] = *reinterpret_cast<const bf16x8*>(&sBh[rb]);
                fbl[j] = *reinterpret_cast<const bf16x8*>(&sBl[rb]);
            }
#pragma unroll
            for (int i = 0; i < 2; i++)
#pragma unroll
                for (int j = 0; j < 4; j++) {
                    acc[i][j] = __builtin_amdgcn_mfma_f32_16x16x32_bf16(fah[i], fbh[j], acc[i][j], 0, 0, 0);
                    acc[i][j] = __builtin_amdgcn_mfma_f32_16x16x32_bf16(fah[i], fbl[j], acc[i][j], 0, 0, 0);
                    acc[i][j] = __builtin_amdgcn_mfma_f32_16x16x32_bf16(fal[i], fbh[j], acc[i][j], 0, 0, 0);
                }
        }
        __syncthreads();
    }

    const int mw = (wave >> 1) * 32;
    const int nw = (wave & 1) * 64;
#pragma unroll
    for (int j = 0; j < 4; j++) {
        const int col = n0 + nw + 16*j + (lane & 15);
        const float bv = bo[col];
#pragma unroll
        for (int i = 0; i < 2; i++) {
            const int rowb = m0 + mw + 16*i + ((lane >> 4) << 2);
#pragma unroll
            for (int r4 = 0; r4 < 4; r4++)
                Of[(size_t)(rowb + r4) * EE + col] = acc[i][j][r4] + bv;
        }
    }
}

// ---------------- fused flash attention, sum-only softmax ----------------
// Phase 1: SINGLE-pass bf16 QK^T (hi only) -> row sums. Error analysis: dropped
// hi*lo cross terms are zero-mean RNE noise (~8e-4 log2-units) averaged over
// N_eff~1e3 flat-softmax entries -> ~1e-4 relative on the sum. Phase 2 keeps
// the 3-pass split scores for the actual weights.
__global__ __launch_bounds__(256, 2)
void attn_fused(const uint16_t* __restrict__ Qh, const uint16_t* __restrict__ Ql,
                const uint16_t* __restrict__ Kh, const uint16_t* __restrict__ Kl,
                const uint16_t* __restrict__ Vh,
                float* __restrict__ attn,
                uint16_t* __restrict__ Oh, uint16_t* __restrict__ Ol)
{
    __shared__ __align__(16) uint16_t smem[36864];   // 73728 B -> 2 blocks/CU
    uint16_t* bufA = smem;          // K tile: hi [128][72] @0, lo @+9216 | phase2 W overlay [128][136]
    uint16_t* bufB = smem + 18432;  // phase1 dbuf partner (hi only) | phase2 V^T [64][136]

    const int t = threadIdx.x, lane = t & 63, wave = t >> 6;
    const int qt = blockIdx.x, bh = blockIdx.y;
    const size_t hb = (size_t)bh * SS * DD;
    const uint16_t* kbh = Kh + hb;
    const uint16_t* kbl = Kl + hb;
    const uint16_t* vbs = Vh + hb;

    const int l15 = lane & 15;
    const int l16 = lane >> 4;
    const int sr = t >> 3;        // 0..31
    const int sc = (t & 7) * 8;   // 0..56

    // ---- K staging regs (global->reg->LDS) ----
    ushort8 krh[4], krl[4];
    auto kload_hi = [&](int kt) {
#pragma unroll
        for (int p = 0; p < 4; p++) {
            const size_t g = (size_t)(kt*128 + sr + 32*p) * DD + sc;
            krh[p] = *reinterpret_cast<const ushort8*>(&kbh[g]);
        }
    };
    auto kwrite_hi = [&](uint16_t* buf) {
#pragma unroll
        for (int p = 0; p < 4; p++) {
            const int o = (sr + 32*p)*LDP + sc;
            *reinterpret_cast<ushort8*>(&buf[o]) = krh[p];
        }
    };
    auto kload = [&](int kt) {
#pragma unroll
        for (int p = 0; p < 4; p++) {
            const size_t g = (size_t)(kt*128 + sr + 32*p) * DD + sc;
            krh[p] = *reinterpret_cast<const ushort8*>(&kbh[g]);
            krl[p] = *reinterpret_cast<const ushort8*>(&kbl[g]);
        }
    };
    auto kwrite = [&](uint16_t* buf) {
#pragma unroll
        for (int p = 0; p < 4; p++) {
            const int o = (sr + 32*p)*LDP + sc;
            *reinterpret_cast<ushort8*>(&buf[o]) = krh[p];
            *reinterpret_cast<ushort8*>(&buf[9216 + o]) = krl[p];
        }
    };

    // ---- Q fragments in registers (persistent) ----
    bf16x8 qfh[2][2], qfl[2][2];
#pragma unroll
    for (int i = 0; i < 2; i++)
#pragma unroll
        for (int ks = 0; ks < 2; ks++) {
            const size_t qa = hb + (size_t)(qt*128 + wave*32 + 16*i + l15) * DD + ks*32 + l16*8;
            qfh[i][ks] = *reinterpret_cast<const bf16x8*>(&Qh[qa]);
            qfl[i][ks] = *reinterpret_cast<const bf16x8*>(&Ql[qa]);
        }

    f32x4 zero = {0.f, 0.f, 0.f, 0.f};
    f32x4 lsum[2] = {zero, zero};

    // ================= phase 1: row sums of exp2(scores), single-pass bf16 =================
    kload_hi(0);
#pragma unroll 1
    for (int kt = 0; kt < 16; kt++) {
        uint16_t* buf = (kt & 1) ? bufB : bufA;
        kwrite_hi(buf);
        if (kt < 15) kload_hi(kt + 1);
        __syncthreads();

        f32x4 accs[2][8];
#pragma unroll
        for (int i = 0; i < 2; i++)
#pragma unroll
            for (int j = 0; j < 8; j++) accs[i][j] = zero;

#pragma unroll
        for (int ks = 0; ks < 2; ks++) {
            const int kk = ks*32 + l16*8;
#pragma unroll
            for (int j = 0; j < 8; j++) {
                const int rb = (16*j + l15) * LDP + kk;
                bf16x8 fbh = *reinterpret_cast<const bf16x8*>(&buf[rb]);
#pragma unroll
                for (int i = 0; i < 2; i++)
                    accs[i][j] = __builtin_amdgcn_mfma_f32_16x16x32_bf16(qfh[i][ks], fbh, accs[i][j], 0, 0, 0);
            }
        }

#pragma unroll
        for (int i = 0; i < 2; i++)
#pragma unroll
            for (int j = 0; j < 8; j++)
#pragma unroll
                for (int r = 0; r < 4; r++)
                    lsum[i][r] += __builtin_amdgcn_exp2f(accs[i][j][r]);
    }

    // finalize: reduce over the 16-lane row group, invert
    f32x4 iv[2];
#pragma unroll
    for (int i = 0; i < 2; i++)
#pragma unroll
        for (int r = 0; r < 4; r++) {
            float s = lsum[i][r];
#pragma unroll
            for (int o = 1; o < 16; o <<= 1) s += __shfl_xor(s, o);
            iv[i][r] = 1.0f / s;
        }

    f32x4 acco[2][4];
#pragma unroll
    for (int i = 0; i < 2; i++)
#pragma unroll
        for (int j = 0; j < 4; j++) acco[i][j] = zero;

    float* wbase = attn + ((size_t)bh * SS + qt*128) * SS;

    // ---- V staging: pair-packed b32 writes (conflict-free) ----
    const int pk = t & 63;             // k-pair index (k = 2pk, 2pk+1)
    const int dbase = (t >> 6) * 16;   // d-quarter
    ushort8 vr[2][2];
    auto vload = [&](int kt) {
#pragma unroll
        for (int u = 0; u < 2; u++)
#pragma unroll
            for (int s = 0; s < 2; s++)
                vr[u][s] = *reinterpret_cast<const ushort8*>(
                    &vbs[(size_t)(kt*128 + 2*pk + s) * DD + dbase + u*8]);
    };
    auto vwrite = [&]() {
#pragma unroll
        for (int u = 0; u < 2; u++)
#pragma unroll
            for (int e = 0; e < 8; e++) {
                const int d = dbase + u*8 + e;
                const uint32_t pack = (uint32_t)(unsigned short)vr[u][0][e]
                                    | ((uint32_t)(unsigned short)vr[u][1][e] << 16);
                *reinterpret_cast<uint32_t*>(&bufB[d*LDW + 2*pk]) = pack;
            }
    };

    __syncthreads();   // phase boundary: all phase-1 reads of bufB done

    // ================= phase 2: recompute (3-pass), write weights, PV =================
    kload(0); vload(0);
#pragma unroll 1
    for (int kt = 0; kt < 16; kt++) {
        kwrite(bufA);
        vwrite();
        __syncthreads();                       // bar1: K/V staged

        f32x4 accs[2][8];
#pragma unroll
        for (int i = 0; i < 2; i++)
#pragma unroll
            for (int j = 0; j < 8; j++) accs[i][j] = zero;
#pragma unroll
        for (int ks = 0; ks < 2; ks++) {
            const int kk = ks*32 + l16*8;
#pragma unroll
            for (int j = 0; j < 8; j++) {
                const int rb = (16*j + l15) * LDP + kk;
                bf16x8 fbh = *reinterpret_cast<const bf16x8*>(&bufA[rb]);
                bf16x8 fbl = *reinterpret_cast<const bf16x8*>(&bufA[9216 + rb]);
#pragma unroll
                for (int i = 0; i < 2; i++) {
                    accs[i][j] = __builtin_amdgcn_mfma_f32_16x16x32_bf16(qfh[i][ks], fbh, accs[i][j], 0, 0, 0);
                    accs[i][j] = __builtin_amdgcn_mfma_f32_16x16x32_bf16(qfh[i][ks], fbl, accs[i][j], 0, 0, 0);
                    accs[i][j] = __builtin_amdgcn_mfma_f32_16x16x32_bf16(qfl[i][ks], fbh, accs[i][j], 0, 0, 0);
                }
            }
        }

        // prefetch next tile's K/V while VALU works (T14)
        if (kt < 15) { kload(kt + 1); vload(kt + 1); }

        // normalize: w = exp2(s) * inv_sum (no max shift)
#pragma unroll
        for (int i = 0; i < 2; i++)
#pragma unroll
            for (int j = 0; j < 8; j++)
#pragma unroll
                for (int r = 0; r < 4; r++)
                    accs[i][j][r] = __builtin_amdgcn_exp2f(accs[i][j][r]) * iv[i][r];

        __syncthreads();                       // bar2: all K reads done

        // W bf16 -> bufA overlay
#pragma unroll
        for (int i = 0; i < 2; i++)
#pragma unroll
            for (int r = 0; r < 4; r++) {
                const int row = wave*32 + 16*i + l16*4 + r;
#pragma unroll
                for (int j = 0; j < 8; j++)
                    bufA[row*LDW + l15 + 16*j] = f2bf(accs[i][j][r]);
            }
        __syncthreads();                       // bar3: W/V visible

        // weight stores issued HERE: PV MFMA below hides the store latency,
        // bar4's vmcnt drain is then mostly pre-satisfied.
#pragma unroll
        for (int i = 0; i < 2; i++)
#pragma unroll
            for (int r = 0; r < 4; r++) {
                const int row = wave*32 + 16*i + l16*4 + r;
                float* wout = wbase + (size_t)row * SS + kt*128 + l15;
#pragma unroll
                for (int j = 0; j < 8; j++) wout[16*j] = accs[i][j][r];
            }

        // PV: O += W @ V
#pragma unroll
        for (int ks = 0; ks < 4; ks++) {
            const int kk = ks*32 + l16*8;
            bf16x8 wa[2], vbf[4];
#pragma unroll
            for (int i = 0; i < 2; i++)
                wa[i] = *reinterpret_cast<const bf16x8*>(&bufA[(wave*32 + 16*i + l15)*LDW + kk]);
#pragma unroll
            for (int j = 0; j < 4; j++)
                vbf[j] = *reinterpret_cast<const bf16x8*>(&bufB[(16*j + l15)*LDW + kk]);
#pragma unroll
            for (int i = 0; i < 2; i++)
#pragma unroll
                for (int j = 0; j < 4; j++)
                    acco[i][j] = __builtin_amdgcn_mfma_f32_16x16x32_bf16(wa[i], vbf[j], acco[i][j], 0, 0, 0);
        }
        __syncthreads();                       // bar4: PV reads + stores drained
    }

    // epilogue: attn_output split-bf16 into [b, s, h*64+d]
    const int b = bh >> 3, h = bh & 7;
#pragma unroll
    for (int i = 0; i < 2; i++)
#pragma unroll
        for (int j = 0; j < 4; j++)
#pragma unroll
            for (int r4 = 0; r4 < 4; r4++) {
                const int srow = qt*128 + wave*32 + 16*i + (l16 << 2) + r4;
                const int col = h*64 + 16*j + l15;
                const size_t idx = ((size_t)b * SS + srow) * (size_t)EE + col;
                const float val = acco[i][j][r4];
                const uint16_t hh = f2bf(val);
                Oh[idx] = hh;
                Ol[idx] = f2bf(val - bf2f(hh));
            }
}

extern "C" void kernel_launch(void* const* d_in, const int* in_sizes, int n_in,
                              void* d_out, int out_size, void* d_ws, size_t ws_size,
                              hipStream_t stream)
{
    const float* x  = (const float*)d_in[0];
    const float* Wq = (const float*)d_in[1];
    const float* bq = (const float*)d_in[2];
    const float* Wk = (const float*)d_in[3];
    const float* bk = (const float*)d_in[4];
    const float* Wv = (const float*)d_in[5];
    const float* bv = (const float*)d_in[6];
    const float* Wo = (const float*)d_in[7];
    const float* bo = (const float*)d_in[8];

    float* outF = (float*)d_out;
    float* attn = outF + (size_t)MM * EE;   // output 1 region (normalized weights)

    const size_t NXE = (size_t)MM * EE;     // 4,194,304
    const size_t NW  = (size_t)EE * EE;     // 262,144
    uint16_t* p = (uint16_t*)d_ws;
    uint16_t* xh    = p;          p += NXE;
    uint16_t* xl    = p;          p += NXE;
    uint16_t* wqkvh = p;          p += 3*NW;
    uint16_t* wqkvl = p;          p += 3*NW;
    uint16_t* woh   = p;          p += NW;
    uint16_t* wol   = p;          p += NW;
    uint16_t* qh    = p;          p += NXE;
    uint16_t* ql    = p;          p += NXE;
    uint16_t* kh    = p;          p += NXE;
    uint16_t* kl    = p;          p += NXE;
    uint16_t* vh    = p;          p += NXE;
    uint16_t* ah    = p;          p += NXE;
    uint16_t* al    = p;          p += NXE;

    split_all<<<4096 + 4*256, 256, 0, stream>>>(x, Wq, Wk, Wv, Wo,
                                                xh, xl, wqkvh, wqkvl, woh, wol);

    // Q scaled by 0.125*log2(e): scores land in log2 units -> softmax uses exp2 directly
    const float qscale = 0.125f * 1.44269504088896340736f;
    gemm_qkv<<<dim3(MM/64, (3*EE)/128), 256, 0, stream>>>(
        xh, xl, wqkvh, wqkvl, bq, bk, bv, qscale, qh, ql, kh, kl, vh);

    attn_fused<<<dim3(SS/128, NB*NH), 256, 0, stream>>>(qh, ql, kh, kl, vh, attn, ah, al);

    gemm_out<<<dim3(MM/64, EE/128), 256, 0, stream>>>(ah, al, woh, wol, bo, outF);
}